// Round 2
// baseline (71443.695 us; speedup 1.0000x reference)
//
#include <hip/hip_runtime.h>
#include <hip/hip_cooperative_groups.h>
#include <cstdint>
#include <cstddef>

namespace cg = cooperative_groups;

#define T_ 2048
#define N_ 64
#define L_ 300
#define V_ 35
#define E_ 256
#define H_ 512
#define KS_ 128

typedef __attribute__((ext_vector_type(8))) short short8;
typedef __attribute__((ext_vector_type(4))) float float4v;

struct Params {
    const float *key, *values;
    const int *x_lens, *text;
    const float *emb_W;
    const float *W_ih1, *W_hh1, *b_ih1, *b_hh1;
    const float *W_ih2, *W_hh2, *b_ih2, *b_hh2;
    const float *W_ih3, *W_hh3, *b_ih3, *b_hh3;
    const float *b_out;
    // workspace (gate-interleaved weights: row j*4+g)
    unsigned short *Wih1i, *Whh1i, *Wih2i, *Whh2i, *Wih3i, *Whh3i, *embWb;
    float *b1i, *b2i, *b3i;
    unsigned short *keyB, *valB;        // [n][t][k] bf16
    float *c1, *c2, *c3, *h3f;
    unsigned short *h1b0, *h1b1, *h2b0, *h2b1, *h3b0, *h3b1, *x1b;
    float *ctxAcc;                      // [2][64][128]
    float *statsBuf;                    // [2][64][4][2]
    unsigned int *h3cnt, *statsCnt, *ctxCnt;  // 1, 64, 64
    float *out;
};

__device__ __forceinline__ float b2f(unsigned short u) {
    unsigned int i = ((unsigned int)u) << 16;
    float f; __builtin_memcpy(&f, &i, 4); return f;
}
__device__ __forceinline__ unsigned short f2b(float f) {
    unsigned int i; __builtin_memcpy(&i, &f, 4);
    i += 0x7FFFu + ((i >> 16) & 1u);
    return (unsigned short)(i >> 16);
}
__device__ __forceinline__ float sigm(float x) { return 1.0f / (1.0f + __expf(-x)); }
__device__ __forceinline__ float tanh_(float x) {
    float e = __expf(2.0f * x);
    return 1.0f - 2.0f / (e + 1.0f);
}
__device__ __forceinline__ float wredmax(float v) {
#pragma unroll
    for (int o = 32; o > 0; o >>= 1) v = fmaxf(v, __shfl_down(v, o));
    return v;
}
__device__ __forceinline__ float wredsum(float v) {
#pragma unroll
    for (int o = 32; o > 0; o >>= 1) v += __shfl_down(v, o);
    return v;
}
__device__ __forceinline__ float dot8(short8 w8, float4v a, float4v b) {
    return ((b2f((unsigned short)w8[0]) * a[0] + b2f((unsigned short)w8[1]) * a[1])
          + (b2f((unsigned short)w8[2]) * a[2] + b2f((unsigned short)w8[3]) * a[3]))
         + ((b2f((unsigned short)w8[4]) * b[0] + b2f((unsigned short)w8[5]) * b[1])
          + (b2f((unsigned short)w8[6]) * b[2] + b2f((unsigned short)w8[7]) * b[3]));
}

struct SharedAB {
    float part[8][16][17];
    float gv[2][16][17];
};
struct SharedD {
    float h3s[128];
    float att[512];
    float ctxp[32][130];
    float ctxf[128];
    float red[64];
    float lsum[35][8];
};
union SharedU { SharedAB ab; SharedD d; };

// Interleaved-gate LSTM layer phase. WG (mt, ct) computes h for rows
// m in [16mt,16mt+16), hidden j in [8ct, 8ct+8) (gate cols [32ct, 32ct+32)).
// 8 waves = 2 col-halves x 4 K-quarters; LDS reduce; WG-local epilogue.
template <int KX, int KH, int HOUT>
__device__ __forceinline__ void lstm_phase(
    int mt, int ct, int tid,
    const unsigned short* __restrict__ xin,   // [64][KX]
    const unsigned short* __restrict__ hin,   // [64][KH]
    const unsigned short* __restrict__ Wx,    // [4*HOUT][KX] interleaved
    const unsigned short* __restrict__ Wh,    // [4*HOUT][KH] interleaved
    const float* __restrict__ bias,           // [4*HOUT] interleaved
    float* __restrict__ cst,                  // [64][HOUT]
    unsigned short* __restrict__ hout,        // [64][HOUT]
    float* __restrict__ houtF,                // optional [64][HOUT]
    SharedAB& s)
{
    constexpr int KT = KX + KH, KQ = KT / 4;
    const int lane = tid & 63, wv = tid >> 6, q = lane >> 4, l15 = lane & 15;
    const int ch = wv & 1, kq = wv >> 1;
    const int col = ct * 32 + ch * 16 + l15;
    const int m = mt * 16 + l15;

    float4v acc = {0.f, 0.f, 0.f, 0.f};
    const int k0 = kq * KQ;
#pragma unroll
    for (int kk = 0; kk < KQ; kk += 32) {
        const int k = k0 + kk;
        const unsigned short *ar, *br;
        if (k < KX) {
            ar = xin + (size_t)m * KX + k + q * 8;
            br = Wx + (size_t)col * KX + k + q * 8;
        } else {
            ar = hin + (size_t)m * KH + (k - KX) + q * 8;
            br = Wh + (size_t)col * KH + (k - KX) + q * 8;
        }
        acc = __builtin_amdgcn_mfma_f32_16x16x32_bf16(
            *(const short8*)ar, *(const short8*)br, acc, 0, 0, 0);
    }
#pragma unroll
    for (int r = 0; r < 4; r++) s.part[wv][l15][q * 4 + r] = acc[r];
    __syncthreads();
    {
        const int chh = tid >> 8, kcol = (tid >> 4) & 15, mm = tid & 15;
        float g = s.part[chh][kcol][mm] + s.part[2 + chh][kcol][mm]
                + s.part[4 + chh][kcol][mm] + s.part[6 + chh][kcol][mm]
                + bias[ct * 32 + chh * 16 + kcol];
        s.gv[chh][kcol][mm] = g;
    }
    __syncthreads();
    if (tid < 128) {
        const int mm = tid & 15, jj = tid >> 4;
        const float gi = s.gv[jj >> 2][(jj & 3) * 4 + 0][mm];
        const float gf = s.gv[jj >> 2][(jj & 3) * 4 + 1][mm];
        const float gg = s.gv[jj >> 2][(jj & 3) * 4 + 2][mm];
        const float go = s.gv[jj >> 2][(jj & 3) * 4 + 3][mm];
        const size_t ix = (size_t)(mt * 16 + mm) * HOUT + (ct * 8 + jj);
        float c = sigm(gf) * cst[ix] + sigm(gi) * tanh_(gg);
        cst[ix] = c;
        float h = sigm(go) * tanh_(c);
        hout[ix] = f2b(h);
        if (houtF) houtF[ix] = h;
    }
    __syncthreads();
}

__global__ __launch_bounds__(512) void decoder_main(Params p)
{
    cg::grid_group grid = cg::this_grid();
    __shared__ SharedU sm;
    const int w = blockIdx.x;      // 0..255
    const int tid = threadIdx.x;   // 0..511
    const int lane = tid & 63, wv = tid >> 6;
    float* const attbase = p.out + (size_t)N_ * L_ * V_;

    for (int l = 0; l < L_; ++l) {
        const int pr = l & 1;
        const unsigned short* h1prev = pr ? p.h1b1 : p.h1b0;
        unsigned short* h1cur = pr ? p.h1b0 : p.h1b1;
        const unsigned short* h2prev = pr ? p.h2b1 : p.h2b0;
        unsigned short* h2cur = pr ? p.h2b0 : p.h2b1;
        const unsigned short* h3prev = pr ? p.h3b1 : p.h3b0;
        unsigned short* h3cur = pr ? p.h3b0 : p.h3b1;

        // ---- Phase A: LSTM1 (x = [emb||ctx], K=384+512) ----
        lstm_phase<E_ + KS_, H_, H_>(w >> 6, w & 63, tid, p.x1b, h1prev,
                                     p.Wih1i, p.Whh1i, p.b1i, p.c1, h1cur,
                                     nullptr, sm.ab);
        grid.sync();

        // ---- Phase B: LSTM2 (K=512+512) ----
        lstm_phase<H_, H_, H_>(w >> 6, w & 63, tid, h1cur, h2prev,
                               p.Wih2i, p.Whh2i, p.b2i, p.c2, h2cur,
                               nullptr, sm.ab);
        grid.sync();

        // ---- Phase C: LSTM3 (64 WGs, K=512+128) + handshake ----
        if (w < 64) {
            lstm_phase<H_, KS_, KS_>(w >> 4, w & 15, tid, h2cur, h3prev,
                                     p.Wih3i, p.Whh3i, p.b3i, p.c3, h3cur,
                                     p.h3f, sm.ab);
            if (tid == 0) { __threadfence(); atomicAdd(p.h3cnt, 1u); }
        }
        if (tid == 0) {
            while (__hip_atomic_load(p.h3cnt, __ATOMIC_ACQUIRE,
                                     __HIP_MEMORY_SCOPE_AGENT) < 64u * (l + 1))
                __builtin_amdgcn_s_sleep(1);
        }
        __syncthreads();
        __threadfence();

        // ---- Phase D: attention, 4 WGs per n ----
        {
            SharedD& sd = sm.d;
            const int n = w & 63, qw = w >> 6;
            const int len = p.x_lens[n];

            if (tid < KS_) sd.h3s[tid] = p.h3f[n * KS_ + tid];
            __syncthreads();

            // energy, 1 t per thread
            const int t = qw * 512 + tid;
            float e = -1e30f;
            if (t < len) {
                const unsigned short* kr = p.keyB + ((size_t)n * T_ + t) * KS_;
                const float4v* hv = (const float4v*)sd.h3s;
                float s0 = 0.f, s1 = 0.f, s2 = 0.f, s3 = 0.f;
#pragma unroll
                for (int kk = 0; kk < 16; kk += 4) {
                    s0 += dot8(*(const short8*)(kr + (kk + 0) * 8), hv[2 * kk + 0], hv[2 * kk + 1]);
                    s1 += dot8(*(const short8*)(kr + (kk + 1) * 8), hv[2 * kk + 2], hv[2 * kk + 3]);
                    s2 += dot8(*(const short8*)(kr + (kk + 2) * 8), hv[2 * kk + 4], hv[2 * kk + 5]);
                    s3 += dot8(*(const short8*)(kr + (kk + 3) * 8), hv[2 * kk + 6], hv[2 * kk + 7]);
                }
                e = (s0 + s1) + (s2 + s3);
            }
            // local max / sum
            float ml = wredmax(e);
            if (lane == 0) sd.red[wv] = ml;
            __syncthreads();
            if (tid == 0) {
                float M = sd.red[0];
                for (int i = 1; i < 8; i++) M = fmaxf(M, sd.red[i]);
                sd.red[16] = M;
            }
            __syncthreads();
            const float Ml = sd.red[16];
            const float ex = (t < len) ? __expf(e - Ml) : 0.f;
            float sl = wredsum(ex);
            if (lane == 0) sd.red[24 + wv] = sl;
            __syncthreads();
            if (tid == 0) {
                float S = 0.f;
                for (int i = 0; i < 8; i++) S += sd.red[24 + i];
                float* sb = p.statsBuf + ((size_t)pr * 64 + n) * 8 + qw * 2;
                __hip_atomic_store(sb + 0, Ml, __ATOMIC_RELAXED, __HIP_MEMORY_SCOPE_AGENT);
                __hip_atomic_store(sb + 1, S, __ATOMIC_RELAXED, __HIP_MEMORY_SCOPE_AGENT);
                __threadfence();
                atomicAdd(p.statsCnt + n, 1u);
                while (__hip_atomic_load(p.statsCnt + n, __ATOMIC_ACQUIRE,
                                         __HIP_MEMORY_SCOPE_AGENT) < 4u * (l + 1))
                    __builtin_amdgcn_s_sleep(1);
                const float* sbn = p.statsBuf + ((size_t)pr * 64 + n) * 8;
                float Mq[4], Sq[4];
#pragma unroll
                for (int i = 0; i < 4; i++) {
                    Mq[i] = __hip_atomic_load(sbn + 2 * i + 0, __ATOMIC_RELAXED, __HIP_MEMORY_SCOPE_AGENT);
                    Sq[i] = __hip_atomic_load(sbn + 2 * i + 1, __ATOMIC_RELAXED, __HIP_MEMORY_SCOPE_AGENT);
                }
                float Mg = fmaxf(fmaxf(Mq[0], Mq[1]), fmaxf(Mq[2], Mq[3]));
                float Sg = 0.f;
#pragma unroll
                for (int i = 0; i < 4; i++) Sg += Sq[i] * __expf(Mq[i] - Mg);
                sd.red[32] = Mg;
                sd.red[33] = 1.0f / Sg;
            }
            __syncthreads();
            const float Mg = sd.red[32], rSg = sd.red[33];
            const float pt = ex * __expf(Ml - Mg) * rSg;
            sd.att[tid] = pt;
            if (t < len) attbase[((size_t)n * L_ + l) * T_ + t] = pt;
            __syncthreads();

            // ctx partial over this slice
            {
                const int tg = tid >> 4, e8 = tid & 15;
                float a8[8] = {0, 0, 0, 0, 0, 0, 0, 0};
                const unsigned short* vbase = p.valB + (size_t)n * T_ * KS_ + e8 * 8;
                for (int i = 0; i < 16; i++) {
                    const int tl = tg + 32 * i;
                    const int tt = qw * 512 + tl;
                    if (tt >= len) break;
                    const float wgt = sd.att[tl];
                    short8 v8 = *(const short8*)(vbase + (size_t)tt * KS_);
                    a8[0] += wgt * b2f((unsigned short)v8[0]);
                    a8[1] += wgt * b2f((unsigned short)v8[1]);
                    a8[2] += wgt * b2f((unsigned short)v8[2]);
                    a8[3] += wgt * b2f((unsigned short)v8[3]);
                    a8[4] += wgt * b2f((unsigned short)v8[4]);
                    a8[5] += wgt * b2f((unsigned short)v8[5]);
                    a8[6] += wgt * b2f((unsigned short)v8[6]);
                    a8[7] += wgt * b2f((unsigned short)v8[7]);
                }
#pragma unroll
                for (int j = 0; j < 8; j++) sd.ctxp[tg][e8 * 8 + j] = a8[j];
            }
            __syncthreads();
            if (tid < KS_) {
                float s = 0.f;
#pragma unroll 8
                for (int g2 = 0; g2 < 32; g2++) s += sd.ctxp[g2][tid];
                atomicAdd(p.ctxAcc + ((size_t)pr * 64 + n) * KS_ + tid, s);
            }
            __syncthreads();
            if (tid == 0) { __threadfence(); atomicAdd(p.ctxCnt + n, 1u); }

            if (qw == 0) {
                if (tid == 0) {
                    while (__hip_atomic_load(p.ctxCnt + n, __ATOMIC_ACQUIRE,
                                             __HIP_MEMORY_SCOPE_AGENT) < 4u * (l + 1))
                        __builtin_amdgcn_s_sleep(1);
                }
                __syncthreads();
                __threadfence();
                if (tid < KS_) {
                    float cval = __hip_atomic_load(
                        p.ctxAcc + ((size_t)pr * 64 + n) * KS_ + tid,
                        __ATOMIC_RELAXED, __HIP_MEMORY_SCOPE_AGENT);
                    sd.ctxf[tid] = cval;
                    p.x1b[(size_t)n * (E_ + KS_) + E_ + tid] = f2b(cval);
                    p.ctxAcc[((size_t)(1 - pr) * 64 + n) * KS_ + tid] = 0.f;
                }
                __syncthreads();
                if (tid < V_ * 8) {
                    const int v = tid >> 3, oc = tid & 7;
                    const float* er = p.emb_W + (size_t)v * E_ + oc * 32;
                    const float* src = (oc < 4) ? (sd.h3s + oc * 32) : (sd.ctxf + oc * 32 - 128);
                    float s = 0.f;
#pragma unroll
                    for (int j = 0; j < 32; j++) s += src[j] * er[j];
                    sd.lsum[v][oc] = s;
                }
                __syncthreads();
                if (tid < V_) {
                    float s = p.b_out[tid];
#pragma unroll
                    for (int j = 0; j < 8; j++) s += sd.lsum[tid][j];
                    p.out[((size_t)n * L_ + l) * V_ + tid] = s;
                }
            } else if (qw == 1) {
                if (l + 1 < L_ && tid < E_) {
                    int row = p.text[n * L_ + l + 1];
                    p.x1b[(size_t)n * (E_ + KS_) + tid] = p.embWb[(size_t)row * E_ + tid];
                }
            }
        }
        grid.sync();
    }
}

// ---------------- setup kernels ----------------
// dst row (j*4+g) <- src row (g*J+j), K columns, f32 -> bf16
__global__ void setup_interleave(const float* __restrict__ src,
                                 unsigned short* __restrict__ dst, int J, int K)
{
    const int r = blockIdx.x;
    const int j = r >> 2, g = r & 3;
    const float* s = src + ((size_t)(g * J + j)) * K;
    unsigned short* d = dst + (size_t)r * K;
    for (int k = threadIdx.x; k < K; k += blockDim.x) d[k] = f2b(s[k]);
}

__global__ void setup_bias(const float* __restrict__ bi, const float* __restrict__ bh,
                           float* __restrict__ dst, int J)
{
    const int r = blockIdx.x * blockDim.x + threadIdx.x;
    if (r < 4 * J) {
        const int j = r >> 2, g = r & 3;
        dst[r] = bi[g * J + j] + bh[g * J + j];
    }
}

__global__ void setup_cast(const float* __restrict__ src,
                           unsigned short* __restrict__ dst, int count)
{
    const int i = blockIdx.x * blockDim.x + threadIdx.x;
    if (i < count) dst[i] = f2b(src[i]);
}

__global__ void setup_kv(Params p)
{
    const size_t stride = (size_t)gridDim.x * blockDim.x;
    const size_t total = (size_t)T_ * N_ * KS_;
    for (size_t idx = (size_t)blockIdx.x * blockDim.x + threadIdx.x; idx < total; idx += stride) {
        const int t = (int)(idx >> 13);
        const int rem = (int)(idx & 8191);
        const int n = rem >> 7, k = rem & 127;
        const size_t dst = ((size_t)n * T_ + t) * KS_ + k;
        p.keyB[dst] = f2b(p.key[idx]);
        p.valB[dst] = f2b(p.values[idx]);
    }
}

__global__ void setup_x1(Params p)
{
    const int n = blockIdx.x, tid = threadIdx.x;  // 64 x 256
    const int row = p.text[n * L_];
    p.x1b[(size_t)n * (E_ + KS_) + tid] = p.embWb[(size_t)row * E_ + tid];
}

// ---------------- host ----------------
extern "C" void kernel_launch(void* const* d_in, const int* in_sizes, int n_in,
                              void* d_out, int out_size, void* d_ws, size_t ws_size,
                              hipStream_t stream)
{
    (void)in_sizes; (void)n_in; (void)out_size; (void)ws_size;
    Params p;
    p.key    = (const float*)d_in[0];
    p.values = (const float*)d_in[1];
    p.x_lens = (const int*)d_in[2];
    p.text   = (const int*)d_in[3];
    p.emb_W  = (const float*)d_in[4];
    p.W_ih1  = (const float*)d_in[5];
    p.W_hh1  = (const float*)d_in[6];
    p.b_ih1  = (const float*)d_in[7];
    p.b_hh1  = (const float*)d_in[8];
    p.W_ih2  = (const float*)d_in[9];
    p.W_hh2  = (const float*)d_in[10];
    p.b_ih2  = (const float*)d_in[11];
    p.b_hh2  = (const float*)d_in[12];
    p.W_ih3  = (const float*)d_in[13];
    p.W_hh3  = (const float*)d_in[14];
    p.b_ih3  = (const float*)d_in[15];
    p.b_hh3  = (const float*)d_in[16];
    p.b_out  = (const float*)d_in[17];
    p.out    = (float*)d_out;

    char* w = (char*)d_ws;
    auto alloc = [&](size_t bytes) -> char* {
        char* r = w;
        w += (bytes + 255) & ~(size_t)255;
        return r;
    };
    p.Wih1i = (unsigned short*)alloc((size_t)2048 * 384 * 2);
    p.Whh1i = (unsigned short*)alloc((size_t)2048 * 512 * 2);
    p.Wih2i = (unsigned short*)alloc((size_t)2048 * 512 * 2);
    p.Whh2i = (unsigned short*)alloc((size_t)2048 * 512 * 2);
    p.Wih3i = (unsigned short*)alloc((size_t)512 * 512 * 2);
    p.Whh3i = (unsigned short*)alloc((size_t)512 * 128 * 2);
    p.embWb = (unsigned short*)alloc((size_t)V_ * E_ * 2);
    p.b1i = (float*)alloc(2048 * 4);
    p.b2i = (float*)alloc(2048 * 4);
    p.b3i = (float*)alloc(512 * 4);
    p.keyB = (unsigned short*)alloc((size_t)N_ * T_ * KS_ * 2);
    p.valB = (unsigned short*)alloc((size_t)N_ * T_ * KS_ * 2);
    char* zstart = w;
    p.c1  = (float*)alloc((size_t)N_ * H_ * 4);
    p.c2  = (float*)alloc((size_t)N_ * H_ * 4);
    p.c3  = (float*)alloc((size_t)N_ * KS_ * 4);
    p.h3f = (float*)alloc((size_t)N_ * KS_ * 4);
    p.h1b0 = (unsigned short*)alloc((size_t)N_ * H_ * 2);
    p.h1b1 = (unsigned short*)alloc((size_t)N_ * H_ * 2);
    p.h2b0 = (unsigned short*)alloc((size_t)N_ * H_ * 2);
    p.h2b1 = (unsigned short*)alloc((size_t)N_ * H_ * 2);
    p.h3b0 = (unsigned short*)alloc((size_t)N_ * KS_ * 2);
    p.h3b1 = (unsigned short*)alloc((size_t)N_ * KS_ * 2);
    p.x1b  = (unsigned short*)alloc((size_t)N_ * (E_ + KS_) * 2);
    p.ctxAcc   = (float*)alloc((size_t)2 * N_ * KS_ * 4);
    p.statsBuf = (float*)alloc((size_t)2 * N_ * 4 * 2 * 4);
    p.h3cnt    = (unsigned int*)alloc(4);
    p.statsCnt = (unsigned int*)alloc(64 * 4);
    p.ctxCnt   = (unsigned int*)alloc(64 * 4);
    size_t zbytes = (size_t)(w - zstart);

    hipMemsetAsync(zstart, 0, zbytes, stream);
    hipMemsetAsync((char*)d_out + (size_t)N_ * L_ * V_ * 4, 0,
                   (size_t)N_ * L_ * T_ * 4, stream);

    setup_interleave<<<dim3(2048), dim3(256), 0, stream>>>(p.W_ih1, p.Wih1i, 512, 384);
    setup_interleave<<<dim3(2048), dim3(256), 0, stream>>>(p.W_hh1, p.Whh1i, 512, 512);
    setup_interleave<<<dim3(2048), dim3(256), 0, stream>>>(p.W_ih2, p.Wih2i, 512, 512);
    setup_interleave<<<dim3(2048), dim3(256), 0, stream>>>(p.W_hh2, p.Whh2i, 512, 512);
    setup_interleave<<<dim3(512),  dim3(256), 0, stream>>>(p.W_ih3, p.Wih3i, 128, 512);
    setup_interleave<<<dim3(512),  dim3(128), 0, stream>>>(p.W_hh3, p.Whh3i, 128, 128);
    setup_bias<<<dim3(8), dim3(256), 0, stream>>>(p.b_ih1, p.b_hh1, p.b1i, 512);
    setup_bias<<<dim3(8), dim3(256), 0, stream>>>(p.b_ih2, p.b_hh2, p.b2i, 512);
    setup_bias<<<dim3(2), dim3(256), 0, stream>>>(p.b_ih3, p.b_hh3, p.b3i, 128);
    setup_cast<<<dim3(35), dim3(256), 0, stream>>>(p.emb_W, p.embWb, V_ * E_);
    setup_kv<<<dim3(2048), dim3(256), 0, stream>>>(p);
    setup_x1<<<dim3(64), dim3(256), 0, stream>>>(p);

    void* args[] = { (void*)&p };
    hipLaunchCooperativeKernel((void*)decoder_main, dim3(256), dim3(512), args, 0, stream);
}